// Round 20
// baseline (136.484 us; speedup 1.0000x reference)
//
#include <hip/hip_runtime.h>

#define KH_   10
#define KW_   4
#define W_    64
#define K1_   5120       // C*KH*KW
#define WK_   61
#define JP_   5824       // 91*64
#define NZ    819200
#define KS1   8          // k-split gemm1 (chunk 640, 20 iters of 32; M-split x2)
#define KS2   8          // jp-split gemm2 (chunk ~23 iters of 32)

typedef __attribute__((ext_vector_type(8))) short short8;
typedef __attribute__((ext_vector_type(4))) short short4v;
typedef __attribute__((ext_vector_type(4))) float f32x4;

__device__ __forceinline__ unsigned short f2bf(float f) {
    unsigned int u = __float_as_uint(f);
    return (unsigned short)((u + 0x8000u) >> 16);
}

// ---------------------------------------------------------------------------
// pack: Qb2 (Q frag layout) + X (gemm1 B).  (identical to measured R10)
// ---------------------------------------------------------------------------
__global__ __launch_bounds__(256) void pack_kernel(const float* __restrict__ z1,
                                                   const float* __restrict__ z2,
                                                   unsigned short* __restrict__ Qb2,
                                                   unsigned short* __restrict__ X) {
    int tid = blockIdx.x * 256 + threadIdx.x;   // < 921600
    if (tid < 102400) {                       // --- Qb2 octs (frag layout) ---
        int ko = tid / 160, i = tid - ko * 160;
        int d0 = ko * 8;
        int c = d0 / 40, rr = d0 - c * 40;
        int kh0 = rr >> 2;                    // even
        int ih = i >> 4, iw = i & 15;
        int a0 = c * 6400 + (ih * KH_ + kh0) * W_ + iw * KW_;
        unsigned short v[8];
#pragma unroll
        for (int s = 0; s < 4; ++s) v[s] = f2bf(z1[a0 + s]);
#pragma unroll
        for (int s = 0; s < 4; ++s) v[4 + s] = f2bf(z1[a0 + W_ + s]);
        *(short8*)(Qb2 + (size_t)tid * 8) = *(short8*)v;
    } else {                                  // --- X octs ---
        int o = tid - 102400;                 // o = (c*100+h)*64 + w
        int w = o & 63, ch = o >> 6;
        int h = ch % 100;
        unsigned short v[8];
        if (w <= 60 && h < 99) {              // fast path: no clamping needed
            const float* p0 = z2 + ch * 64 + w;
#pragma unroll
            for (int s = 0; s < 4; ++s) v[s] = f2bf(p0[s]);
#pragma unroll
            for (int s = 0; s < 4; ++s) v[4 + s] = f2bf(p0[64 + s]);
        } else {                              // boundary path (w>60 or h==99)
            int ch2 = (h < 99) ? ch + 1 : ch;
#pragma unroll
            for (int s = 0; s < 4; ++s) v[s] = f2bf(z2[ch * 64 + min(w + s, 63)]);
#pragma unroll
            for (int s = 0; s < 4; ++s) v[4 + s] = f2bf(z2[ch2 * 64 + min(w + s, 63)]);
        }
        *(short8*)(X + (size_t)o * 8) = *(short8*)v;
    }
}

// ---------------------------------------------------------------------------
// GEMM1: no LDS, no barriers. grid (KS1=8, 92) = 736 blocks x 256 thr.
// Block tile 80(m) x 128(j) x 640(k); wave tile 80x32 (acc[5][2]).
// 2-deep register software pipeline — fragments for iteration it+1
// load while iteration it's MFMAs issue (double-buffered af/bf sets,
// static names, even 20-iter pairing).  Same math order -> bit-identical.
// ---------------------------------------------------------------------------
__global__ __launch_bounds__(256) void gemm1_kernel(const unsigned short* __restrict__ Qb2,
                                                    const unsigned short* __restrict__ X,
                                                    float* __restrict__ Sp) {
    const int t = threadIdx.x;
    const int ksp = blockIdx.x;      // 0..7
    const int by  = blockIdx.y;      // 0..91
    const int hkt = by >> 1;         // 0..45
    const int mhf = by & 1;          // row half (80 rows each)
    const int hk0 = hkt * 2;
    const int wave = t >> 6, lane = t & 63;
    const int nh = wave;             // 0..3: 32-col strip within 128
    const int l15 = lane & 15, q = lane >> 4;

    int band[2], wk[2];
#pragma unroll
    for (int n = 0; n < 2; ++n) {
        int jpn = nh * 32 + n * 16 + l15;
        band[n] = jpn >> 6;
        wk[n]   = jpn & 63;
    }
    int rowA[5];
#pragma unroll
    for (int b = 0; b < 5; ++b) rowA[b] = mhf * 80 + b * 16 + l15;

    f32x4 acc[5][2];
#pragma unroll
    for (int b = 0; b < 5; ++b)
#pragma unroll
        for (int n = 0; n < 2; ++n) acc[b][n] = (f32x4){0.f, 0.f, 0.f, 0.f};

#define G1LOAD(itv, AF, BF) do {                                               \
        const unsigned short* Ab_ = Qb2 + ((size_t)(ksp * 80 + (itv) * 4 + q) * 160) * 8; \
        _Pragma("unroll")                                                      \
        for (int b_ = 0; b_ < 5; ++b_)                                         \
            AF[b_] = *(const short8*)(Ab_ + rowA[b_] * 8);                     \
        int d0_ = ksp * 640 + (itv) * 32 + q * 8;                              \
        int c_ = (int)((unsigned)d0_ / 40u), rr_ = d0_ - c_ * 40;              \
        int kh0_ = rr_ >> 2;                                                   \
        const unsigned short* Bb_ = X + ((size_t)(c_ * 100 + hk0 + kh0_) * 64) * 8; \
        _Pragma("unroll")                                                      \
        for (int n_ = 0; n_ < 2; ++n_)                                         \
            BF[n_] = *(const short8*)(Bb_ + (band[n_] * 64 + wk[n_]) * 8);     \
    } while (0)

#define G1MFMA(AF, BF) do {                                                    \
        _Pragma("unroll")                                                      \
        for (int b_ = 0; b_ < 5; ++b_)                                         \
            _Pragma("unroll")                                                  \
            for (int n_ = 0; n_ < 2; ++n_)                                     \
                acc[b_][n_] = __builtin_amdgcn_mfma_f32_16x16x32_bf16(AF[b_], BF[n_], acc[b_][n_], 0, 0, 0); \
    } while (0)

    short8 afA[5], bfA[2], afB[5], bfB[2];
    G1LOAD(0, afA, bfA);
    for (int it = 0; it < 20; it += 2) {
        if (it + 1 < 20) G1LOAD(it + 1, afB, bfB);
        G1MFMA(afA, bfA);
        if (it + 2 < 20) G1LOAD(it + 2, afA, bfA);
        G1MFMA(afB, bfB);
    }
#undef G1LOAD
#undef G1MFMA

    float* base = Sp + (size_t)ksp * (160 * JP_);
#pragma unroll
    for (int b = 0; b < 5; ++b) {
        int i0 = mhf * 80 + b * 16 + q * 4;
#pragma unroll
        for (int n = 0; n < 2; ++n) {
            int jg = hkt * 128 + nh * 32 + n * 16 + l15;
            if (jg < JP_) {
#pragma unroll
                for (int r = 0; r < 4; ++r)
                    base[(size_t)(i0 + r) * JP_ + jg] = acc[b][n][r];
            }
        }
    }
}

// ---------------------------------------------------------------------------
// smpz: softmax (blocks 0..159, one q-row each, 512 thr) + Z2s packing
// (blocks 160..959).  (identical to the measured 128.5us R10 version)
// ---------------------------------------------------------------------------
__global__ __launch_bounds__(512) void smpz_kernel(const float* __restrict__ z2,
                                                   const float* __restrict__ Sp,
                                                   unsigned short* __restrict__ Atn2,
                                                   unsigned short* __restrict__ Z2s) {
    const int bid = blockIdx.x;
    const int t = threadIdx.x;
    if (bid < 160) {                          // ---- softmax role ----
        const int i = bid;
        const int wave = t >> 6, lane = t & 63;
        __shared__ float red2[8];
        f32x4 v[3];
        float s = 0.f;
#pragma unroll
        for (int jj = 0; jj < 3; ++jj) {
            int q4 = t + jj * 512;
            f32x4 r = (f32x4){0.f, 0.f, 0.f, 0.f};
            if (q4 < 1456) {
                f32x4 a = (f32x4){0.f, 0.f, 0.f, 0.f};
#pragma unroll
                for (int p = 0; p < KS1; ++p)
                    a += *(const f32x4*)(Sp + (size_t)p * (160 * JP_) + (size_t)i * JP_ + q4 * 4);
                a *= (1.0f / 5120.0f);
                bool pad_hi = (((q4 * 4) & 63) == 60);   // cols 61,62,63 of a band
#pragma unroll
                for (int e = 0; e < 4; ++e) {
                    bool ok = !(pad_hi && e > 0);
                    float x = ok ? __expf(a[e]) : 0.f;
                    r[e] = x;
                    s += x;
                }
            }
            v[jj] = r;
        }
#pragma unroll
        for (int off = 32; off >= 1; off >>= 1) s += __shfl_xor(s, off);
        if (lane == 0) red2[wave] = s;
        __syncthreads();
        float inv = 1.0f / (red2[0] + red2[1] + red2[2] + red2[3] +
                            red2[4] + red2[5] + red2[6] + red2[7]);
#pragma unroll
        for (int jj = 0; jj < 3; ++jj) {
            int q4 = t + jj * 512;
            if (q4 < 1456) {
                short4v u;
                u.x = (short)f2bf(v[jj].x * inv);
                u.y = (short)f2bf(v[jj].y * inv);
                u.z = (short)f2bf(v[jj].z * inv);
                u.w = (short)f2bf(v[jj].w * inv);
                *(short4v*)(Atn2 + ((size_t)(q4 >> 1) * 160 + i) * 8 + (q4 & 1) * 4) = u;
            }
        }
    } else {                                  // ---- Z2s-pack role ----
        int o = (bid - 160) * 512 + t;        // 0..409599
        int kw = o / 102400, r8 = o - kw * 102400;
        int e0 = r8 * 8;
        int w0 = e0 & 63, rowbase = e0 - w0;
        unsigned short v[8];
        if (w0 < 56 || kw == 0) {             // fast path: window fits in row
            const float* p = z2 + rowbase + w0 + kw;
#pragma unroll
            for (int s = 0; s < 8; ++s) v[s] = f2bf(p[s]);
        } else {                              // boundary: clamp at col 63
#pragma unroll
            for (int s = 0; s < 8; ++s) v[s] = f2bf(z2[rowbase + min(w0 + s + kw, 63)]);
        }
        *(short8*)(Z2s + (size_t)kw * NZ + e0) = *(short8*)v;
    }
}

// ---------------------------------------------------------------------------
// GEMM2: grid (KS2=8, 80) = 640 blocks x 256 thr; tile 64(d) x 160(i),
// ~23-iter k-loop, DOUBLE-BUFFERED LDS for the KV^T A-tile (R16 proved the
// staging earns its barriers: block-wide share + 64B coalescing).
// 2-deep register pipeline on the global Atn2 B-fragments (bfA/bfB
// static names; it+1's B loads issue right after the barrier and fly
// during iteration it's 10 MFMAs).  Same math order -> bit-identical.
// ---------------------------------------------------------------------------
__global__ __launch_bounds__(256) void gemm2_kernel(const unsigned short* __restrict__ Atn2,
                                                    const unsigned short* __restrict__ Z2s,
                                                    float* __restrict__ Op) {
    __shared__ short As[2][64 * 40];   // KV^T tile [d_local][jp_local], stride 40 (2-way, free)
    const int t = threadIdx.x;
    const int ksp = blockIdx.x;      // 0..7
    const int dt = blockIdx.y;       // 0..79
    const int dbase = dt * 64;
    const int it0 = (182 * ksp) >> 3;
    const int it1 = (182 * (ksp + 1)) >> 3;
    const int wave = t >> 6, lane = t & 63;
    const int mh = wave & 1, nh = wave >> 1;       // wave tile 32(d) x 80(i)
    const int l15 = lane & 15, q = lane >> 4;

    // staging geometry (one short8 per thread per k-iter)
    const int dl_s = t >> 2, jg_s = t & 3;
    const int d_s = dbase + dl_s;
    const unsigned du_s = (unsigned)d_s;
    const int c_s = du_s / 40u, rr_s = d_s - c_s * 40;
    const int kh_s = rr_s >> 2, kw_s = rr_s & 3;
    const int sbase = kw_s * NZ + c_s * 6400 + kh_s * W_;

    f32x4 acc[2][5];
#pragma unroll
    for (int m = 0; m < 2; ++m)
#pragma unroll
        for (int n = 0; n < 5; ++n) acc[m][n] = (f32x4){0.f, 0.f, 0.f, 0.f};

#define STAGE2(buf, itv) do {                                                  \
        int jp0_ = (itv) * 32 + jg_s * 8;                                      \
        int hk_ = jp0_ >> 6, wk0_ = jp0_ & 63;                                 \
        *(short8*)&As[buf][dl_s * 40 + jg_s * 8] =                             \
            *(const short8*)(Z2s + sbase + hk_ * W_ + wk0_);                   \
    } while (0)

#define G2BF(itv, BF) do {                                                     \
        const unsigned short* Bb_ = Atn2 + ((size_t)((((itv) * 32) >> 3) + q) * 160) * 8; \
        _Pragma("unroll")                                                      \
        for (int n_ = 0; n_ < 5; ++n_)                                         \
            BF[n_] = *(const short8*)(Bb_ + ((nh * 5 + n_) * 16 + l15) * 8);   \
    } while (0)

#define G2STEP(pb, BF) do {                                                    \
        short8 af_[2];                                                         \
        _Pragma("unroll")                                                      \
        for (int m_ = 0; m_ < 2; ++m_)                                         \
            af_[m_] = *(const short8*)&As[pb][(mh * 32 + m_ * 16 + l15) * 40 + q * 8]; \
        _Pragma("unroll")                                                      \
        for (int m_ = 0; m_ < 2; ++m_)                                         \
            _Pragma("unroll")                                                  \
            for (int n_ = 0; n_ < 5; ++n_)                                     \
                acc[m_][n_] = __builtin_amdgcn_mfma_f32_16x16x32_bf16(af_[m_], BF[n_], acc[m_][n_], 0, 0, 0); \
    } while (0)

    short8 bfA[5], bfB[5];
    STAGE2(0, it0);
    G2BF(it0, bfA);
    int it = it0;
    while (it < it1) {
        {   // phase A: compute it with bfA; prefetch it+1 -> bfB
            int pb = (it - it0) & 1;
            __syncthreads();                   // As[pb] ready
            if (it + 1 < it1) { STAGE2(pb ^ 1, it + 1); G2BF(it + 1, bfB); }
            G2STEP(pb, bfA);
        }
        ++it; if (it >= it1) break;
        {   // phase B: compute it with bfB; prefetch it+1 -> bfA
            int pb = (it - it0) & 1;
            __syncthreads();
            if (it + 1 < it1) { STAGE2(pb ^ 1, it + 1); G2BF(it + 1, bfA); }
            G2STEP(pb, bfB);
        }
        ++it;
    }
#undef STAGE2
#undef G2BF
#undef G2STEP

    float* base = Op + (size_t)ksp * ((size_t)NZ);
#pragma unroll
    for (int m = 0; m < 2; ++m) {
        int d0 = dbase + mh * 32 + m * 16 + q * 4;
#pragma unroll
        for (int n = 0; n < 5; ++n) {
            int i = (nh * 5 + n) * 16 + l15;
#pragma unroll
            for (int r = 0; r < 4; ++r)
                base[(size_t)(d0 + r) * 160 + i] = acc[m][n][r];
        }
    }
}

// ---------------------------------------------------------------------------
// reduce: out[c][ih*10+kh][iw*4+kw] = sum_p Op[p][d*160+i]; vectorized x4
// ---------------------------------------------------------------------------
__global__ __launch_bounds__(256) void reduce_kernel(const float* __restrict__ Op,
                                                     float* __restrict__ out) {
    int tid = blockIdx.x * 256 + threadIdx.x;   // < 204800
    int f = tid * 4;
    f32x4 s = (f32x4){0.f, 0.f, 0.f, 0.f};
#pragma unroll
    for (int p = 0; p < KS2; ++p) s += *(const f32x4*)(Op + (size_t)p * NZ + f);
    int d = f / 160, i0 = f - d * 160;          // x4 block never straddles d
    int c = d / 40, rr = d - c * 40;
    int kh = rr >> 2, kw = rr & 3;
#pragma unroll
    for (int r = 0; r < 4; ++r) {
        int i = i0 + r;
        int ih = i >> 4, iw = i & 15;
        out[c * 6400 + (ih * KH_ + kh) * W_ + iw * KW_ + kw] = s[r];
    }
}

extern "C" void kernel_launch(void* const* d_in, const int* in_sizes, int n_in,
                              void* d_out, int out_size, void* d_ws, size_t ws_size,
                              hipStream_t stream) {
    const float* z1 = (const float*)d_in[0];
    const float* z2 = (const float*)d_in[1];
    float* out = (float*)d_out;

    char* w = (char*)d_ws;
    unsigned short* Qb2  = (unsigned short*)(w);                 // 1,638,400 B
    unsigned short* Z2s  = (unsigned short*)(w + 1638400);       // 6,553,600 B
    unsigned short* X    = (unsigned short*)(w + 8192000);       // 13,107,200 B
    unsigned short* Atn2 = (unsigned short*)(w + 21299200);      // 1,863,680 B
    float* Sp = (float*)(w + 23162880);                          // 29,818,880 B (8 partials)
    float* Op = (float*)(w + 52981760);                          // 26,214,400 B (8 partials)

    pack_kernel<<<3600, 256, 0, stream>>>(z1, z2, Qb2, X);
    gemm1_kernel<<<dim3(KS1, 92), 256, 0, stream>>>(Qb2, X, Sp);
    smpz_kernel<<<960, 512, 0, stream>>>(z2, Sp, Atn2, Z2s);
    gemm2_kernel<<<dim3(KS2, 80), 256, 0, stream>>>(Atn2, Z2s, Op);
    reduce_kernel<<<800, 256, 0, stream>>>(Op, out);
}

// Round 21
// 128.344 us; speedup vs baseline: 1.0634x; 1.0634x over previous
//
#include <hip/hip_runtime.h>

#define KH_   10
#define KW_   4
#define W_    64
#define K1_   5120       // C*KH*KW
#define WK_   61
#define JP_   5824       // 91*64
#define NZ    819200
#define KS1   8          // k-split gemm1 (chunk 640, 20 iters of 32; M-split x2)
#define KS2   8          // jp-split gemm2 (chunk ~23 iters of 32)

typedef __attribute__((ext_vector_type(8))) short short8;
typedef __attribute__((ext_vector_type(4))) short short4v;
typedef __attribute__((ext_vector_type(4))) float f32x4;

__device__ __forceinline__ unsigned short f2bf(float f) {
    unsigned int u = __float_as_uint(f);
    return (unsigned short)((u + 0x8000u) >> 16);
}

// ---------------------------------------------------------------------------
// pack: Qb2 (Q frag layout) + X (gemm1 B).  (measured-best R10 version)
// ---------------------------------------------------------------------------
__global__ __launch_bounds__(256) void pack_kernel(const float* __restrict__ z1,
                                                   const float* __restrict__ z2,
                                                   unsigned short* __restrict__ Qb2,
                                                   unsigned short* __restrict__ X) {
    int tid = blockIdx.x * 256 + threadIdx.x;   // < 921600
    if (tid < 102400) {                       // --- Qb2 octs (frag layout) ---
        int ko = tid / 160, i = tid - ko * 160;
        int d0 = ko * 8;
        int c = d0 / 40, rr = d0 - c * 40;
        int kh0 = rr >> 2;                    // even
        int ih = i >> 4, iw = i & 15;
        int a0 = c * 6400 + (ih * KH_ + kh0) * W_ + iw * KW_;
        unsigned short v[8];
#pragma unroll
        for (int s = 0; s < 4; ++s) v[s] = f2bf(z1[a0 + s]);
#pragma unroll
        for (int s = 0; s < 4; ++s) v[4 + s] = f2bf(z1[a0 + W_ + s]);
        *(short8*)(Qb2 + (size_t)tid * 8) = *(short8*)v;
    } else {                                  // --- X octs ---
        int o = tid - 102400;                 // o = (c*100+h)*64 + w
        int w = o & 63, ch = o >> 6;
        int h = ch % 100;
        unsigned short v[8];
        if (w <= 60 && h < 99) {              // fast path: no clamping needed
            const float* p0 = z2 + ch * 64 + w;
#pragma unroll
            for (int s = 0; s < 4; ++s) v[s] = f2bf(p0[s]);
#pragma unroll
            for (int s = 0; s < 4; ++s) v[4 + s] = f2bf(p0[64 + s]);
        } else {                              // boundary path (w>60 or h==99)
            int ch2 = (h < 99) ? ch + 1 : ch;
#pragma unroll
            for (int s = 0; s < 4; ++s) v[s] = f2bf(z2[ch * 64 + min(w + s, 63)]);
#pragma unroll
            for (int s = 0; s < 4; ++s) v[4 + s] = f2bf(z2[ch2 * 64 + min(w + s, 63)]);
        }
        *(short8*)(X + (size_t)o * 8) = *(short8*)v;
    }
}

// ---------------------------------------------------------------------------
// GEMM1: no LDS, no barriers. grid (KS1=8, 92) = 736 blocks x 256 thr.
// Block tile 80(m) x 128(j) x 640(k); wave tile 80x32 (acc[5][2]).
// Simple single-iteration loop — R20 proved manual 2-deep pipelining
// regresses (+8us): the compiler already hoists loads across iterations.
// ---------------------------------------------------------------------------
__global__ __launch_bounds__(256) void gemm1_kernel(const unsigned short* __restrict__ Qb2,
                                                    const unsigned short* __restrict__ X,
                                                    float* __restrict__ Sp) {
    const int t = threadIdx.x;
    const int ksp = blockIdx.x;      // 0..7
    const int by  = blockIdx.y;      // 0..91
    const int hkt = by >> 1;         // 0..45
    const int mhf = by & 1;          // row half (80 rows each)
    const int hk0 = hkt * 2;
    const int wave = t >> 6, lane = t & 63;
    const int nh = wave;             // 0..3: 32-col strip within 128
    const int l15 = lane & 15, q = lane >> 4;

    int band[2], wk[2];
#pragma unroll
    for (int n = 0; n < 2; ++n) {
        int jpn = nh * 32 + n * 16 + l15;
        band[n] = jpn >> 6;
        wk[n]   = jpn & 63;
    }
    int rowA[5];
#pragma unroll
    for (int b = 0; b < 5; ++b) rowA[b] = mhf * 80 + b * 16 + l15;

    f32x4 acc[5][2];
#pragma unroll
    for (int b = 0; b < 5; ++b)
#pragma unroll
        for (int n = 0; n < 2; ++n) acc[b][n] = (f32x4){0.f, 0.f, 0.f, 0.f};

    for (int it = 0; it < 20; ++it) {
        const unsigned short* Ab = Qb2 + ((size_t)(ksp * 80 + it * 4 + q) * 160) * 8;
        short8 af[5], bf[2];
#pragma unroll
        for (int b = 0; b < 5; ++b)
            af[b] = *(const short8*)(Ab + rowA[b] * 8);
        int d0 = ksp * 640 + it * 32 + q * 8;
        unsigned du = (unsigned)d0;
        int c = du / 40u, rr = d0 - c * 40;
        int kh0 = rr >> 2;           // even
        const unsigned short* Bb = X + ((size_t)(c * 100 + hk0 + kh0) * 64) * 8;
#pragma unroll
        for (int n = 0; n < 2; ++n)
            bf[n] = *(const short8*)(Bb + (band[n] * 64 + wk[n]) * 8);
#pragma unroll
        for (int b = 0; b < 5; ++b)
#pragma unroll
            for (int n = 0; n < 2; ++n)
                acc[b][n] = __builtin_amdgcn_mfma_f32_16x16x32_bf16(af[b], bf[n], acc[b][n], 0, 0, 0);
    }
    float* base = Sp + (size_t)ksp * (160 * JP_);
#pragma unroll
    for (int b = 0; b < 5; ++b) {
        int i0 = mhf * 80 + b * 16 + q * 4;
#pragma unroll
        for (int n = 0; n < 2; ++n) {
            int jg = hkt * 128 + nh * 32 + n * 16 + l15;
            if (jg < JP_) {
#pragma unroll
                for (int r = 0; r < 4; ++r)
                    base[(size_t)(i0 + r) * JP_ + jg] = acc[b][n][r];
            }
        }
    }
}

// ---------------------------------------------------------------------------
// smpz: softmax (blocks 0..159, one q-row each, 512 thr) + Z2s packing
// (blocks 160..959).  (measured-best R10 version)
// ---------------------------------------------------------------------------
__global__ __launch_bounds__(512) void smpz_kernel(const float* __restrict__ z2,
                                                   const float* __restrict__ Sp,
                                                   unsigned short* __restrict__ Atn2,
                                                   unsigned short* __restrict__ Z2s) {
    const int bid = blockIdx.x;
    const int t = threadIdx.x;
    if (bid < 160) {                          // ---- softmax role ----
        const int i = bid;
        const int wave = t >> 6, lane = t & 63;
        __shared__ float red2[8];
        f32x4 v[3];
        float s = 0.f;
#pragma unroll
        for (int jj = 0; jj < 3; ++jj) {
            int q4 = t + jj * 512;
            f32x4 r = (f32x4){0.f, 0.f, 0.f, 0.f};
            if (q4 < 1456) {
                f32x4 a = (f32x4){0.f, 0.f, 0.f, 0.f};
#pragma unroll
                for (int p = 0; p < KS1; ++p)
                    a += *(const f32x4*)(Sp + (size_t)p * (160 * JP_) + (size_t)i * JP_ + q4 * 4);
                a *= (1.0f / 5120.0f);
                bool pad_hi = (((q4 * 4) & 63) == 60);   // cols 61,62,63 of a band
#pragma unroll
                for (int e = 0; e < 4; ++e) {
                    bool ok = !(pad_hi && e > 0);
                    float x = ok ? __expf(a[e]) : 0.f;
                    r[e] = x;
                    s += x;
                }
            }
            v[jj] = r;
        }
#pragma unroll
        for (int off = 32; off >= 1; off >>= 1) s += __shfl_xor(s, off);
        if (lane == 0) red2[wave] = s;
        __syncthreads();
        float inv = 1.0f / (red2[0] + red2[1] + red2[2] + red2[3] +
                            red2[4] + red2[5] + red2[6] + red2[7]);
#pragma unroll
        for (int jj = 0; jj < 3; ++jj) {
            int q4 = t + jj * 512;
            if (q4 < 1456) {
                short4v u;
                u.x = (short)f2bf(v[jj].x * inv);
                u.y = (short)f2bf(v[jj].y * inv);
                u.z = (short)f2bf(v[jj].z * inv);
                u.w = (short)f2bf(v[jj].w * inv);
                *(short4v*)(Atn2 + ((size_t)(q4 >> 1) * 160 + i) * 8 + (q4 & 1) * 4) = u;
            }
        }
    } else {                                  // ---- Z2s-pack role ----
        int o = (bid - 160) * 512 + t;        // 0..409599
        int kw = o / 102400, r8 = o - kw * 102400;
        int e0 = r8 * 8;
        int w0 = e0 & 63, rowbase = e0 - w0;
        unsigned short v[8];
        if (w0 < 56 || kw == 0) {             // fast path: window fits in row
            const float* p = z2 + rowbase + w0 + kw;
#pragma unroll
            for (int s = 0; s < 8; ++s) v[s] = f2bf(p[s]);
        } else {                              // boundary: clamp at col 63
#pragma unroll
            for (int s = 0; s < 8; ++s) v[s] = f2bf(z2[rowbase + min(w0 + s + kw, 63)]);
        }
        *(short8*)(Z2s + (size_t)kw * NZ + e0) = *(short8*)v;
    }
}

// ---------------------------------------------------------------------------
// GEMM2: grid (KS2=8, 80) = 640 blocks x 256 thr; tile 64(d) x 160(i),
// ~23-iter k-loop, DOUBLE-BUFFERED LDS (one barrier per k-iter); attn
// B-frags direct from Atn2 (coalesced). fp32 partials Op; no atomics.
// (measured-best R10 version — staging earns its barriers, R16)
// ---------------------------------------------------------------------------
__global__ __launch_bounds__(256) void gemm2_kernel(const unsigned short* __restrict__ Atn2,
                                                    const unsigned short* __restrict__ Z2s,
                                                    float* __restrict__ Op) {
    __shared__ short As[2][64 * 40];   // KV^T tile [d_local][jp_local], stride 40 (2-way, free)
    const int t = threadIdx.x;
    const int ksp = blockIdx.x;      // 0..7
    const int dt = blockIdx.y;       // 0..79
    const int dbase = dt * 64;
    const int it0 = (182 * ksp) >> 3;
    const int it1 = (182 * (ksp + 1)) >> 3;
    const int wave = t >> 6, lane = t & 63;
    const int mh = wave & 1, nh = wave >> 1;       // wave tile 32(d) x 80(i)
    const int l15 = lane & 15, q = lane >> 4;

    // staging geometry (one short8 per thread per k-iter)
    const int dl_s = t >> 2, jg_s = t & 3;
    const int d_s = dbase + dl_s;
    const unsigned du_s = (unsigned)d_s;
    const int c_s = du_s / 40u, rr_s = d_s - c_s * 40;
    const int kh_s = rr_s >> 2, kw_s = rr_s & 3;
    const int sbase = kw_s * NZ + c_s * 6400 + kh_s * W_;

    f32x4 acc[2][5];
#pragma unroll
    for (int m = 0; m < 2; ++m)
#pragma unroll
        for (int n = 0; n < 5; ++n) acc[m][n] = (f32x4){0.f, 0.f, 0.f, 0.f};

#define STAGE2(buf, itv) do {                                                  \
        int jp0_ = (itv) * 32 + jg_s * 8;                                      \
        int hk_ = jp0_ >> 6, wk0_ = jp0_ & 63;                                 \
        *(short8*)&As[buf][dl_s * 40 + jg_s * 8] =                             \
            *(const short8*)(Z2s + sbase + hk_ * W_ + wk0_);                   \
    } while (0)

    STAGE2(0, it0);
    for (int it = it0; it < it1; ++it) {
        int pb = (it - it0) & 1;
        __syncthreads();                       // As[pb] ready
        if (it + 1 < it1) STAGE2(pb ^ 1, it + 1);
        int k0 = it * 32;
        short8 af[2], bf[5];
#pragma unroll
        for (int m = 0; m < 2; ++m)
            af[m] = *(const short8*)&As[pb][(mh * 32 + m * 16 + l15) * 40 + q * 8];
        const unsigned short* Bb = Atn2 + ((size_t)((k0 >> 3) + q) * 160) * 8;
#pragma unroll
        for (int n = 0; n < 5; ++n)
            bf[n] = *(const short8*)(Bb + ((nh * 5 + n) * 16 + l15) * 8);
#pragma unroll
        for (int m = 0; m < 2; ++m)
#pragma unroll
            for (int n = 0; n < 5; ++n)
                acc[m][n] = __builtin_amdgcn_mfma_f32_16x16x32_bf16(af[m], bf[n], acc[m][n], 0, 0, 0);
    }
#undef STAGE2

    float* base = Op + (size_t)ksp * ((size_t)NZ);
#pragma unroll
    for (int m = 0; m < 2; ++m) {
        int d0 = dbase + mh * 32 + m * 16 + q * 4;
#pragma unroll
        for (int n = 0; n < 5; ++n) {
            int i = (nh * 5 + n) * 16 + l15;
#pragma unroll
            for (int r = 0; r < 4; ++r)
                base[(size_t)(d0 + r) * 160 + i] = acc[m][n][r];
        }
    }
}

// ---------------------------------------------------------------------------
// reduce: out[c][ih*10+kh][iw*4+kw] = sum_p Op[p][d*160+i]; vectorized x4
// ---------------------------------------------------------------------------
__global__ __launch_bounds__(256) void reduce_kernel(const float* __restrict__ Op,
                                                     float* __restrict__ out) {
    int tid = blockIdx.x * 256 + threadIdx.x;   // < 204800
    int f = tid * 4;
    f32x4 s = (f32x4){0.f, 0.f, 0.f, 0.f};
#pragma unroll
    for (int p = 0; p < KS2; ++p) s += *(const f32x4*)(Op + (size_t)p * NZ + f);
    int d = f / 160, i0 = f - d * 160;          // x4 block never straddles d
    int c = d / 40, rr = d - c * 40;
    int kh = rr >> 2, kw = rr & 3;
#pragma unroll
    for (int r = 0; r < 4; ++r) {
        int i = i0 + r;
        int ih = i >> 4, iw = i & 15;
        out[c * 6400 + (ih * KH_ + kh) * W_ + iw * KW_ + kw] = s[r];
    }
}

extern "C" void kernel_launch(void* const* d_in, const int* in_sizes, int n_in,
                              void* d_out, int out_size, void* d_ws, size_t ws_size,
                              hipStream_t stream) {
    const float* z1 = (const float*)d_in[0];
    const float* z2 = (const float*)d_in[1];
    float* out = (float*)d_out;

    char* w = (char*)d_ws;
    unsigned short* Qb2  = (unsigned short*)(w);                 // 1,638,400 B
    unsigned short* Z2s  = (unsigned short*)(w + 1638400);       // 6,553,600 B
    unsigned short* X    = (unsigned short*)(w + 8192000);       // 13,107,200 B
    unsigned short* Atn2 = (unsigned short*)(w + 21299200);      // 1,863,680 B
    float* Sp = (float*)(w + 23162880);                          // 29,818,880 B (8 partials)
    float* Op = (float*)(w + 52981760);                          // 26,214,400 B (8 partials)

    pack_kernel<<<3600, 256, 0, stream>>>(z1, z2, Qb2, X);
    gemm1_kernel<<<dim3(KS1, 92), 256, 0, stream>>>(Qb2, X, Sp);
    smpz_kernel<<<960, 512, 0, stream>>>(z2, Sp, Atn2, Z2s);
    gemm2_kernel<<<dim3(KS2, 80), 256, 0, stream>>>(Atn2, Z2s, Op);
    reduce_kernel<<<800, 256, 0, stream>>>(Op, out);
}